// Round 7
// baseline (190.757 us; speedup 1.0000x reference)
//
#include <hip/hip_runtime.h>

#define NB 64
#define NN 256
#define IND 7
#define HIDD 64
#define OUTD 32
#define EPG 8192
#define ETOT 524288
#define CAPQ 2600     // CSR capacity per 64-dst quarter (mean 2112, ~12 sigma)
#define SRCPAD 2624   // CAPQ rounded to 16

typedef _Float16 f16;
typedef f16 f16x2 __attribute__((ext_vector_type(2)));
typedef f16 f16x4 __attribute__((ext_vector_type(4)));
typedef f16 f16x8 __attribute__((ext_vector_type(8)));
typedef float f32x4 __attribute__((ext_vector_type(4)));

// ---------------- block reductions for 16-wave blocks ----------------
__device__ __forceinline__ float bsum16(float v, float* rb){
#pragma unroll
  for (int o = 32; o > 0; o >>= 1) v += __shfl_xor(v, o, 64);
  __syncthreads();
  if ((threadIdx.x & 63) == 0) rb[threadIdx.x >> 6] = v;
  __syncthreads();
  float s = 0.f;
#pragma unroll
  for (int i = 0; i < 16; i++) s += rb[i];
  return s;
}
__device__ __forceinline__ float bmin16(float v, float* rb){
#pragma unroll
  for (int o = 32; o > 0; o >>= 1) v = fminf(v, __shfl_xor(v, o, 64));
  __syncthreads();
  if ((threadIdx.x & 63) == 0) rb[threadIdx.x >> 6] = v;
  __syncthreads();
  float s = rb[0];
#pragma unroll
  for (int i = 1; i < 16; i++) s = fminf(s, rb[i]);
  return s;
}
__device__ __forceinline__ float bmax16(float v, float* rb){
#pragma unroll
  for (int o = 32; o > 0; o >>= 1) v = fmaxf(v, __shfl_xor(v, o, 64));
  __syncthreads();
  if ((threadIdx.x & 63) == 0) rb[threadIdx.x >> 6] = v;
  __syncthreads();
  float s = rb[0];
#pragma unroll
  for (int i = 1; i < 16; i++) s = fmaxf(s, rb[i]);
  return s;
}

__device__ __forceinline__ f16x2 lrelu2(f16x2 s){
  const f16x2 k = {(f16)0.2f, (f16)0.2f};
  return __builtin_elementwise_max(s, s * k);
}
__device__ __forceinline__ f16x2 shfl_h2(f16x2 v, int lane){
  int i = __builtin_bit_cast(int, v);
  i = __shfl(i, lane, 64);
  return __builtin_bit_cast(f16x2, i);
}
// order-preserving float<->uint keys for atomicMin/Max
__device__ __forceinline__ unsigned fkey(float f){
  unsigned b = __float_as_uint(f);
  return (b & 0x80000000u) ? ~b : (b | 0x80000000u);
}
__device__ __forceinline__ float fkinv(unsigned k){
  unsigned b = (k & 0x80000000u) ? (k ^ 0x80000000u) : ~k;
  return __uint_as_float(b);
}

// ---------------- GAT layer 1 + CSR build (fused, single edge read) --------
// grid 512: (gs=bid>>2, quarter=bid&3 -> 64 dsts), 512 thr, 8 thr/dst.
__global__ __launch_bounds__(512, 4) void gat1(
    const float* __restrict__ x1, const float* __restrict__ x2,
    const int* __restrict__ e1, const int* __restrict__ e2,
    const float* __restrict__ Wl, const float* __restrict__ Wr,
    const float* __restrict__ bl, const float* __restrict__ br,
    const float* __restrict__ att, const float* __restrict__ bias,
    f16* __restrict__ hmid,
    int* __restrict__ meta, unsigned char* __restrict__ srcs)
{
  __shared__ __align__(16) f16 xl_s[256 * 72];   // rows padded to 144B
  __shared__ float sc_s[CAPQ];
  __shared__ unsigned int src_su[SRCPAD / 4];
  __shared__ int deg_s[64], start_s[64], cnt_s[64];
  __shared__ unsigned char perm[64];
  unsigned char* src_s = (unsigned char*)src_su;

  const int bid = blockIdx.x;
  const int gs = bid >> 2, lo = (bid & 3) * 64;
  const int side = gs >> 6, g = gs & 63;
  const float* x = side ? x2 : x1;
  const int* eb = side ? e2 : e1;
  const int* es = eb + g * EPG;
  const int* ed = eb + ETOT + g * EPG;
  const int t = threadIdx.x;

  if (t < 64) deg_s[t] = 0;

  // ---- single global edge read -> registers (packed dst<<8|src)
  unsigned short epk[17];
  int nE = 0;
#pragma unroll
  for (int i = 0; i < 17; i++){
    int e = t + i * 512;
    if (e < EPG + 256){
      int sl, dl;
      if (e < EPG){ sl = es[e] & 255; dl = ed[e] & 255; }
      else { sl = dl = e - EPG; }
      epk[i] = (unsigned short)((dl << 8) | sl);
      nE = i + 1;
    }
  }

  // ---- xl = x@Wl + bl: thread t -> node t>>1, dim-half t&1 (32 dims), f16 LDS
  {
    const int node = t >> 1, dh = t & 1;
    float xv[IND];
    const float* xr_ = x + (g * 256 + node) * IND;
#pragma unroll
    for (int k = 0; k < IND; k++) xv[k] = xr_[k];
#pragma unroll
    for (int ch = 0; ch < 4; ch++){
      f16x8 o;
#pragma unroll
      for (int j = 0; j < 8; j++){
        int dd = dh * 32 + ch * 8 + j;
        float a = bl[dd];
#pragma unroll
        for (int k = 0; k < IND; k++) a = fmaf(xv[k], Wl[k * HIDD + dd], a);
        o[j] = (f16)a;
      }
      *(f16x8*)&xl_s[node * 72 + dh * 32 + ch * 8] = o;
    }
  }
  __syncthreads();   // deg zero + xl_s visible

  // ---- CSR count pass (from regs)
#pragma unroll
  for (int i = 0; i < 17; i++) if (i < nE){
    int r = (epk[i] >> 8) - lo;
    if ((unsigned)r < 64u) atomicAdd(&deg_s[r], 1);
  }
  __syncthreads();
  // ---- scan + meta + degree-sort permutation
  if (t < 64){
    int v = deg_s[t], s = v;
#pragma unroll
    for (int off = 1; off < 64; off <<= 1){
      int u = __shfl_up(s, off, 64);
      if (t >= off) s += u;
    }
    start_s[t] = s - v;
    cnt_s[t] = s - v;
    meta[bid * 128 + t] = s - v;
    meta[bid * 128 + 64 + t] = v;
    int r = 0;
#pragma unroll 8
    for (int j = 0; j < 64; j++){
      int dj = deg_s[j];
      r += (dj < v) || (dj == v && j < t);
    }
    perm[r] = (unsigned char)t;
  }
  __syncthreads();
  // ---- fill pass (from regs)
#pragma unroll
  for (int i = 0; i < 17; i++) if (i < nE){
    int dl = epk[i] >> 8, r = dl - lo;
    if ((unsigned)r < 64u){
      int p = atomicAdd(&cnt_s[r], 1);
      if (p < CAPQ) src_s[p] = (unsigned char)(epk[i] & 255);
    }
  }
  __syncthreads();
  // ---- dump CSR srcs to global for gat2 (coalesced u32)
  {
    int ttl = start_s[63] + deg_s[63];
    if (ttl > CAPQ) ttl = CAPQ;
    unsigned int* gsrc = (unsigned int*)(srcs + (size_t)bid * SRCPAD);
    int nw = (ttl + 3) >> 2;
    for (int i = t; i < nw; i += 512) gsrc[i] = src_su[i];
  }

  // ---- 8 threads/dst (degree-sorted): my 8 xr dims, assemble 64 via shfl
  const int pairi = perm[t >> 3], sub = t & 7, ln = lo + pairi;
  f16x2 m[4], am[4];
  {
    float xv[IND];
    const float* xq = x + (g * 256 + ln) * IND;
#pragma unroll
    for (int k = 0; k < IND; k++) xv[k] = xq[k];
#pragma unroll
    for (int c = 0; c < 4; c++){
#pragma unroll
      for (int u = 0; u < 2; u++){
        int dd = sub * 8 + 2 * c + u;
        float a = br[dd];
#pragma unroll
        for (int k = 0; k < IND; k++) a = fmaf(xv[k], Wr[k * HIDD + dd], a);
        m[c][u] = (f16)a;
        am[c][u] = (f16)att[dd];
      }
    }
  }
  f16x2 xrh[32], atth[32];
  {
    const int base = (t & 63) & ~7;
#pragma unroll
    for (int ss = 0; ss < 8; ss++){
#pragma unroll
      for (int c = 0; c < 4; c++){
        xrh[ss * 4 + c] = shfl_h2(m[c], base + ss);
        atth[ss * 4 + c] = shfl_h2(am[c], base + ss);
      }
    }
  }

  // ---- scores: edge-split (thread handles every-8th edge, full 64 dims)
  const int s0 = start_s[pairi];
  int sE = s0 + deg_s[pairi];
  if (sE > CAPQ) sE = CAPQ;
  float lmax = -3.0e38f;
  for (int idx = s0 + sub; idx < sE; idx += 8){
    int sl = src_s[idx];
    const f16x8* rp = (const f16x8*)&xl_s[(unsigned)sl * 72];
    float accs[4] = {0.f, 0.f, 0.f, 0.f};
#pragma unroll
    for (int blk = 0; blk < 8; blk++){
      f16x8 rv = rp[blk];
#pragma unroll
      for (int u = 0; u < 4; u++){
        f16x2 v = {rv[2 * u], rv[2 * u + 1]};
        v = v + xrh[blk * 4 + u];
        accs[u] = __builtin_amdgcn_fdot2(lrelu2(v), atth[blk * 4 + u], accs[u], false);
      }
    }
    float sc = (accs[0] + accs[1]) + (accs[2] + accs[3]);
    sc_s[idx] = sc;
    lmax = fmaxf(lmax, sc);
  }
  lmax = fmaxf(lmax, __shfl_xor(lmax, 1, 64));
  lmax = fmaxf(lmax, __shfl_xor(lmax, 2, 64));
  lmax = fmaxf(lmax, __shfl_xor(lmax, 4, 64));
  const float smax = lmax;
  // ---- softmax weights
  float ssum = 0.f;
  for (int idx = s0 + sub; idx < sE; idx += 8){
    float w = __expf(sc_s[idx] - smax);
    ssum += w;
    sc_s[idx] = w;
  }
  ssum += __shfl_xor(ssum, 1, 64);
  ssum += __shfl_xor(ssum, 2, 64);
  ssum += __shfl_xor(ssum, 4, 64);
  float inv = 1.f / ssum;
  // ---- aggregate alpha * xl[src], dim-split 8 ways
  float acc[8];
#pragma unroll
  for (int c = 0; c < 8; c++) acc[c] = 0.f;
  {
    int sl = (s0 < sE) ? src_s[s0] : 0;
    f16x8 row = *(const f16x8*)&xl_s[(unsigned)sl * 72 + sub * 8];
    for (int idx = s0; idx < sE; idx++){
      int sln = (idx + 1 < sE) ? src_s[idx + 1] : 0;
      f16x8 rown = *(const f16x8*)&xl_s[(unsigned)sln * 72 + sub * 8];
      float w = sc_s[idx];
#pragma unroll
      for (int c = 0; c < 8; c++) acc[c] = fmaf(w, (float)row[c], acc[c]);
      row = rown;
    }
  }
  f16x8 o;
#pragma unroll
  for (int c = 0; c < 8; c++)
    o[c] = (f16)fmaxf(acc[c] * inv + bias[sub * 8 + c], 0.f);
  *(f16x8*)(hmid + (size_t)(gs * 256 + ln) * 64 + sub * 8) = o;
}

// ---------------- GAT layer 2 + lin2 (fused, degree-sorted) ----------------
__global__ __launch_bounds__(512, 4) void gat2(
    const int* __restrict__ meta, const unsigned char* __restrict__ srcs,
    const f16* __restrict__ hmid,
    const float* __restrict__ Wl, const float* __restrict__ Wr,
    const float* __restrict__ bl, const float* __restrict__ br,
    const float* __restrict__ att, const float* __restrict__ bias,
    f16* __restrict__ hout)
{
  __shared__ __align__(16) f16 xl_s[256 * 40];   // rows padded to 80B
  __shared__ __align__(16) f16 xr_s[64 * 40];
  __shared__ float sc_s[CAPQ];
  __shared__ unsigned int src_su[SRCPAD / 4];
  __shared__ int start_s[64], deg_s[64];
  __shared__ unsigned char perm[64];
  unsigned char* src_s = (unsigned char*)src_su;

  const int bid = blockIdx.x;
  const int gs = bid >> 2, lo = (bid & 3) * 64;
  const int t = threadIdx.x;

  // ---- CSR load (global -> LDS)
  if (t < 64){
    start_s[t] = meta[bid * 128 + t];
    deg_s[t] = meta[bid * 128 + 64 + t];
  }
  {
    int ttl = meta[bid * 128 + 63] + meta[bid * 128 + 64 + 63];
    if (ttl > CAPQ) ttl = CAPQ;
    const unsigned int* gsrc = (const unsigned int*)(srcs + (size_t)bid * SRCPAD);
    int nw = (ttl + 3) >> 2;
    for (int i = t; i < nw; i += 512) src_su[i] = gsrc[i];
  }

  // ---- in-block lin2 via MFMA: wave w -> node tiles {2w, 2w+1} for xl2;
  //      waves 0..3 also compute xr2 for own dst tile.
  {
    const int w = t >> 6, lane = t & 63;
    const int m = lane & 15, quad = lane >> 4;
    f16x8 a[2][2];
#pragma unroll
    for (int ti = 0; ti < 2; ti++){
      const f16* arow = hmid + (size_t)(gs * 256 + (2 * w + ti) * 16 + m) * 64;
      a[ti][0] = *(const f16x8*)(arow + quad * 8);
      a[ti][1] = *(const f16x8*)(arow + 32 + quad * 8);
    }
#pragma unroll
    for (int H = 0; H < 2; H++){
      const int n = H * 16 + m;
      f16x8 b0, b1;
#pragma unroll
      for (int j = 0; j < 8; j++){
        b0[j] = (f16)Wl[(quad * 8 + j) * 32 + n];
        b1[j] = (f16)Wl[(32 + quad * 8 + j) * 32 + n];
      }
      const float bv = bl[n];
#pragma unroll
      for (int ti = 0; ti < 2; ti++){
        f32x4 acc = {0.f, 0.f, 0.f, 0.f};
        acc = __builtin_amdgcn_mfma_f32_16x16x32_f16(a[ti][0], b0, acc, 0, 0, 0);
        acc = __builtin_amdgcn_mfma_f32_16x16x32_f16(a[ti][1], b1, acc, 0, 0, 0);
#pragma unroll
        for (int r = 0; r < 4; r++)
          xl_s[((2 * w + ti) * 16 + quad * 4 + r) * 40 + n] = (f16)(acc[r] + bv);
      }
    }
    if (w < 4){
      const f16* arow = hmid + (size_t)(gs * 256 + lo + w * 16 + m) * 64;
      f16x8 c0 = *(const f16x8*)(arow + quad * 8);
      f16x8 c1 = *(const f16x8*)(arow + 32 + quad * 8);
#pragma unroll
      for (int H = 0; H < 2; H++){
        const int n = H * 16 + m;
        f16x8 b0, b1;
#pragma unroll
        for (int j = 0; j < 8; j++){
          b0[j] = (f16)Wr[(quad * 8 + j) * 32 + n];
          b1[j] = (f16)Wr[(32 + quad * 8 + j) * 32 + n];
        }
        const float bv = br[n];
        f32x4 acc = {0.f, 0.f, 0.f, 0.f};
        acc = __builtin_amdgcn_mfma_f32_16x16x32_f16(c0, b0, acc, 0, 0, 0);
        acc = __builtin_amdgcn_mfma_f32_16x16x32_f16(c1, b1, acc, 0, 0, 0);
#pragma unroll
        for (int r = 0; r < 4; r++)
          xr_s[(w * 16 + quad * 4 + r) * 40 + n] = (f16)(acc[r] + bv);
      }
    }
  }
  __syncthreads();
  // ---- degree-sort permutation
  if (t < 64){
    int v = deg_s[t], r = 0;
#pragma unroll 8
    for (int j = 0; j < 64; j++){
      int dj = deg_s[j];
      r += (dj < v) || (dj == v && j < t);
    }
    perm[r] = (unsigned char)t;
  }
  __syncthreads();

  // ---- 8 threads/dst (sorted): full 32-dim xr + att in regs
  const int pairi = perm[t >> 3], sub = t & 7, ln = lo + pairi;
  f16x2 xrh[16], atth[16];
  {
    const f16x8* xrp = (const f16x8*)&xr_s[pairi * 40];
#pragma unroll
    for (int q = 0; q < 4; q++){
      f16x8 v = xrp[q];
#pragma unroll
      for (int u = 0; u < 4; u++){
        xrh[q * 4 + u][0] = v[2 * u];
        xrh[q * 4 + u][1] = v[2 * u + 1];
      }
    }
#pragma unroll
    for (int i = 0; i < 16; i++){
      atth[i][0] = (f16)att[2 * i];
      atth[i][1] = (f16)att[2 * i + 1];
    }
  }

  // ---- scores: edge-split
  const int s0 = start_s[pairi];
  int sE = s0 + deg_s[pairi];
  if (sE > CAPQ) sE = CAPQ;
  float lmax = -3.0e38f;
  for (int idx = s0 + sub; idx < sE; idx += 8){
    int sl = src_s[idx];
    const f16x8* rp = (const f16x8*)&xl_s[(unsigned)sl * 40];
    float accs[4] = {0.f, 0.f, 0.f, 0.f};
#pragma unroll
    for (int blk = 0; blk < 4; blk++){
      f16x8 rv = rp[blk];
#pragma unroll
      for (int u = 0; u < 4; u++){
        f16x2 v = {rv[2 * u], rv[2 * u + 1]};
        v = v + xrh[blk * 4 + u];
        accs[u] = __builtin_amdgcn_fdot2(lrelu2(v), atth[blk * 4 + u], accs[u], false);
      }
    }
    float sc = (accs[0] + accs[1]) + (accs[2] + accs[3]);
    sc_s[idx] = sc;
    lmax = fmaxf(lmax, sc);
  }
  lmax = fmaxf(lmax, __shfl_xor(lmax, 1, 64));
  lmax = fmaxf(lmax, __shfl_xor(lmax, 2, 64));
  lmax = fmaxf(lmax, __shfl_xor(lmax, 4, 64));
  const float smax = lmax;
  float ssum = 0.f;
  for (int idx = s0 + sub; idx < sE; idx += 8){
    float w = __expf(sc_s[idx] - smax);
    ssum += w;
    sc_s[idx] = w;
  }
  ssum += __shfl_xor(ssum, 1, 64);
  ssum += __shfl_xor(ssum, 2, 64);
  ssum += __shfl_xor(ssum, 4, 64);
  float inv = 1.f / ssum;

  float acc[4];
#pragma unroll
  for (int c = 0; c < 4; c++) acc[c] = 0.f;
  {
    int sl = (s0 < sE) ? src_s[s0] : 0;
    f16x4 row = *(const f16x4*)&xl_s[(unsigned)sl * 40 + sub * 4];
    for (int idx = s0; idx < sE; idx++){
      int sln = (idx + 1 < sE) ? src_s[idx + 1] : 0;
      f16x4 rown = *(const f16x4*)&xl_s[(unsigned)sln * 40 + sub * 4];
      float w = sc_s[idx];
#pragma unroll
      for (int c = 0; c < 4; c++) acc[c] = fmaf(w, (float)row[c], acc[c]);
      row = rown;
    }
  }
  f16x4 o;
#pragma unroll
  for (int c = 0; c < 4; c++)
    o[c] = (f16)(acc[c] * inv + bias[sub * 4 + c]);
  *(f16x4*)(hout + (size_t)(gs * 256 + ln) * 32 + sub * 4) = o;
}

// ---------------- zerok: init per-batch stat accumulators ----------------
__global__ __launch_bounds__(256) void zerok(unsigned* __restrict__ stats){
  int i = threadIdx.x;           // 64 batches x {sum, sumsq, minkey, maxkey}
  if (i < 256) stats[i] = ((i & 3) == 2) ? 0xFFFFFFFFu : 0u;
}

// ---------------- simk: sim quarter via MFMA + stats atomics ----------------
// grid 256 (batch=bid>>2, quarter=bid&3), 1024 thr (16 waves).
__global__ __launch_bounds__(1024) void simk(
    const f16* __restrict__ H, float* __restrict__ out,
    unsigned* __restrict__ stats)
{
  __shared__ float rb[16];
  const int b = blockIdx.x >> 2, q = blockIdx.x & 3, t = threadIdx.x;
  const int w = t >> 6, lane = t & 63;
  const int m = lane & 15, quad = lane >> 4;
  const int rowT = q * 64 + (w & 3) * 16;
  const int colB = (w >> 2) * 64;

  const f16* h1 = H + (size_t)b * 256 * 32;
  const f16* h2 = H + (size_t)(64 + b) * 256 * 32;

  f16x8 av = *(const f16x8*)(h1 + (size_t)(rowT + m) * 32 + quad * 8);
  f32x4 c[4];
#pragma unroll
  for (int jj = 0; jj < 4; jj++){
    f16x8 bv = *(const f16x8*)(h2 + (size_t)(colB + jj * 16 + m) * 32 + quad * 8);
    f32x4 z = {0.f, 0.f, 0.f, 0.f};
    c[jj] = __builtin_amdgcn_mfma_f32_16x16x32_f16(av, bv, z, 0, 0, 0);
  }

  float sm = 0.f, s2 = 0.f, mn = 3.0e38f, mx = -3.0e38f;
  float* ob = out + (size_t)b * 65536;
#pragma unroll
  for (int jj = 0; jj < 4; jj++)
#pragma unroll
    for (int r = 0; r < 4; r++){
      float s = c[jj][r];
      sm += s; s2 = fmaf(s, s, s2);
      mn = fminf(mn, s); mx = fmaxf(mx, s);
      ob[(rowT + quad * 4 + r) * 256 + colB + jj * 16 + m] = s;
    }
  sm = bsum16(sm, rb);
  s2 = bsum16(s2, rb);
  mn = bmin16(mn, rb);
  mx = bmax16(mx, rb);
  if (t == 0){
    atomicAdd((float*)&stats[b * 4 + 0], sm);
    atomicAdd((float*)&stats[b * 4 + 1], s2);
    atomicMin(&stats[b * 4 + 2], fkey(mn));
    atomicMax(&stats[b * 4 + 3], fkey(mx));
  }
}

// ---------------- sinkk: per-batch histogram Sinkhorn scalars --------------
// grid 64, 1024 thr. Reads back the batch's sim (L2-warm), emits {al,beD,scale}.
__global__ __launch_bounds__(1024) void sinkk(
    const float* __restrict__ sim, const unsigned* __restrict__ stats,
    const float* __restrict__ gamma, const float* __restrict__ beta,
    float* __restrict__ res)
{
  __shared__ float rb[16];
  __shared__ unsigned int hist[8192];
  const int b = blockIdx.x, t = threadIdx.x;

  const float sum = __uint_as_float(stats[b * 4 + 0]);
  const float ssq = __uint_as_float(stats[b * 4 + 1]);
  const float mn = fkinv(stats[b * 4 + 2]);
  const float mx = fkinv(stats[b * 4 + 3]);

  const float mu = sum * (1.f / 65536.f);
  const float var = ssq * (1.f / 65536.f) - mu * mu;
  const float a = gamma[0] * rsqrtf(var + 1e-5f);
  const float cc = beta[0] - a * mu;
  float mnn = a * mn + cc, mxn = a * mx + cc;
  if (a < 0.f){ float tmp = mnn; mnn = mxn; mxn = tmp; }
  const float al = 2.f * a;
  const float be = 2.f * cc - mnn - mxn;
  const float R = fmaxf(mxn - mnn, 1e-12f);       // z in [-R, R]
  const float binscale = 4096.f / R;

  for (int i = t; i < 8192; i += 1024) hist[i] = 0u;
  __syncthreads();
  const f32x4* sp = (const f32x4*)(sim + (size_t)b * 65536);
#pragma unroll
  for (int k = 0; k < 16; k++){
    f32x4 v = sp[k * 1024 + t];
#pragma unroll
    for (int u = 0; u < 4; u++){
      float z = fmaf(al, v[u], be);
      int bi = (int)fmaf(z, binscale, 4096.f);
      bi = min(max(bi, 0), 8191);
      atomicAdd(&hist[bi], 1u);
    }
  }
  __syncthreads();

  const float wbin = R * (1.f / 4096.f);
  float ebs[8], cnts[8];
#pragma unroll
  for (int j = 0; j < 8; j++){
    float zc = fmaf((float)(t * 8 + j) + 0.5f, wbin, -R);
    ebs[j] = __expf(-zc);
    cnts[j] = (float)hist[t * 8 + j];
  }

  float D = 0.f, S = 256.f, eD = 1.f;
  for (int p = 0; p < 5; p++){
    float loc = 0.f;
#pragma unroll
    for (int j = 0; j < 8; j++)
      loc += cnts[j] / (1.f + ebs[j] * eD);
    S = bsum16(loc, rb);
    if (p < 4){
      D += -5.5412635f /* log(256/65280) */ + __logf(65536.f - S) - __logf(S);
      eD = __expf(-D);
    }
  }
  if (t == 0){
    res[b * 4 + 0] = al;
    res[b * 4 + 1] = be + D;
    res[b * 4 + 2] = 256.f / S;
  }
}

// ---------------- outk: elementwise sigmoid+clip, in place -----------------
// grid 512 (batch=bid>>3, eighth=bid&7), 256 thr, f32x4.
__global__ __launch_bounds__(256) void outk(
    float* __restrict__ out, const float* __restrict__ res)
{
  const int b = blockIdx.x >> 3, seg = blockIdx.x & 7, t = threadIdx.x;
  const float al = res[b * 4 + 0];
  const float beD = res[b * 4 + 1];
  const float scale = res[b * 4 + 2];
  f32x4* p = (f32x4*)(out + (size_t)b * 65536 + seg * 8192);
#pragma unroll
  for (int k = 0; k < 8; k++){
    f32x4 v = p[k * 256 + t];
#pragma unroll
    for (int u = 0; u < 4; u++){
      float z = fmaf(al, v[u], beD);
      v[u] = fminf(scale / (1.f + __expf(-z)), 1.f);
    }
    p[k * 256 + t] = v;
  }
}

extern "C" void kernel_launch(void* const* d_in, const int* in_sizes, int n_in,
                              void* d_out, int out_size, void* d_ws, size_t ws_size,
                              hipStream_t stream)
{
  const float* x1   = (const float*)d_in[0];
  const float* x2   = (const float*)d_in[1];
  const int*   e1   = (const int*)d_in[2];
  const int*   e2   = (const int*)d_in[3];
  const float* Wl1  = (const float*)d_in[4];
  const float* Wr1  = (const float*)d_in[5];
  const float* bl1  = (const float*)d_in[6];
  const float* br1  = (const float*)d_in[7];
  const float* att1 = (const float*)d_in[8];
  const float* bias1= (const float*)d_in[9];
  const float* Wl2  = (const float*)d_in[10];
  const float* Wr2  = (const float*)d_in[11];
  const float* bl2  = (const float*)d_in[12];
  const float* br2  = (const float*)d_in[13];
  const float* att2 = (const float*)d_in[14];
  const float* bias2= (const float*)d_in[15];
  const float* gamma= (const float*)d_in[16];
  const float* beta = (const float*)d_in[17];

  char* ws = (char*)d_ws;
  f16* hmid = (f16*)ws;                                        // [0,4M)
  f16* hfin = (f16*)(ws + (size_t)4 * 1024 * 1024);            // [4M,6M)
  int* meta = (int*)(ws + (size_t)6 * 1024 * 1024);            // 256K
  unsigned char* srcs = (unsigned char*)(ws + (size_t)6 * 1024 * 1024 + 512 * 128 * 4);
  unsigned* stats = (unsigned*)(ws + (size_t)8 * 1024 * 1024); // 1K
  float* res = (float*)(ws + (size_t)8 * 1024 * 1024 + 4096);  // 1K
  float* out = (float*)d_out;

  zerok<<<1, 256, 0, stream>>>(stats);
  gat1<<<512, 512, 0, stream>>>(x1, x2, e1, e2, Wl1, Wr1, bl1, br1, att1, bias1,
                                hmid, meta, srcs);
  gat2<<<512, 512, 0, stream>>>(meta, srcs, hmid, Wl2, Wr2, bl2, br2, att2, bias2, hfin);
  simk<<<256, 1024, 0, stream>>>(hfin, out, stats);
  sinkk<<<64, 1024, 0, stream>>>(out, stats, gamma, beta, res);
  outk<<<512, 256, 0, stream>>>(out, res);
}